// Round 4
// baseline (219.006 us; speedup 1.0000x reference)
//
#include <hip/hip_runtime.h>

#define N_TOK 4096
#define C_DIM 256
#define HEADS 8
#define HDIM  32
#define KSPLIT 4
#define QSCALE 0.17677669529663687f
#define L2E    1.4426950408889634f

typedef __attribute__((ext_vector_type(8))) short bf16x8;
typedef __attribute__((ext_vector_type(4))) float f32x4;
typedef __attribute__((ext_vector_type(4))) unsigned int u32x4;
typedef __attribute__((ext_vector_type(8))) unsigned short u16x8;

static __device__ __forceinline__ unsigned short f2bf(float f) {
  union { float f; unsigned int u; } c; c.f = f;
  return (unsigned short)((c.u + 0x8000u) >> 16);
}
static __device__ __forceinline__ float bf2f(unsigned short u) {
  union { unsigned int i; float f; } c; c.i = ((unsigned int)u) << 16;
  return c.f;
}
static __device__ __forceinline__ unsigned int pack2(float a, float b) {
  return (unsigned int)f2bf(a) | ((unsigned int)f2bf(b) << 16);
}

// ---------------------------------------------------------------------------
// Kernel 0: split W = [wq*QSCALE*L2E; wk; wv; wo] (1024x256 fp32) -> hi/lo bf16
// ---------------------------------------------------------------------------
__global__ __launch_bounds__(256) void wsplit(
    const float* __restrict__ wq, const float* __restrict__ wk,
    const float* __restrict__ wv, const float* __restrict__ wo,
    unsigned short* __restrict__ Whi, unsigned short* __restrict__ Wlo)
{
  const int i4  = blockIdx.x * 256 + threadIdx.x;   // 65536 float4s
  const int idx = i4 * 4;
  const int r   = idx >> 8;                          // row 0..1023
  const float* src; int off; float scl = 1.f;
  if (r < 256)      { src = wq; off = idx;          scl = QSCALE * L2E; }
  else if (r < 512) { src = wk; off = idx - 65536;  }
  else if (r < 768) { src = wv; off = idx - 131072; }
  else              { src = wo; off = idx - 196608; }
  float4 v = *reinterpret_cast<const float4*>(&src[off]);
  v.x *= scl; v.y *= scl; v.z *= scl; v.w *= scl;
  ushort4 h, l;
  h.x = f2bf(v.x); l.x = f2bf(v.x - bf2f(h.x));
  h.y = f2bf(v.y); l.y = f2bf(v.y - bf2f(h.y));
  h.z = f2bf(v.z); l.z = f2bf(v.z - bf2f(h.z));
  h.w = f2bf(v.w); l.w = f2bf(v.w - bf2f(h.w));
  *reinterpret_cast<ushort4*>(&Whi[idx]) = h;
  *reinterpret_cast<ushort4*>(&Wlo[idx]) = l;
}

// ---------------------------------------------------------------------------
// Kernel 0b: transpose+split fp32 [256][4096] -> hi/lo bf16 [4096][256]
// (used for x and for outb)
// ---------------------------------------------------------------------------
__global__ __launch_bounds__(256) void tsplit(
    const float* __restrict__ src,
    unsigned short* __restrict__ dhi, unsigned short* __restrict__ dlo)
{
  __shared__ float T[64][69];
  const int c0 = blockIdx.y * 64, n0 = blockIdx.x * 64;
  const int t = threadIdx.x;
  {
    const int cl = t >> 2, ng = (t & 3) * 16;
    #pragma unroll
    for (int jj = 0; jj < 4; jj++) {
      const float4 v = *reinterpret_cast<const float4*>(&src[(c0 + cl) * N_TOK + n0 + ng + jj * 4]);
      T[cl][ng + jj * 4 + 0] = v.x; T[cl][ng + jj * 4 + 1] = v.y;
      T[cl][ng + jj * 4 + 2] = v.z; T[cl][ng + jj * 4 + 3] = v.w;
    }
  }
  __syncthreads();
  {
    const int nl = t >> 2, cg = (t & 3) * 16;
    u16x8 h0, h1, l0, l1;
    #pragma unroll
    for (int j = 0; j < 8; j++) {
      const float v = T[cg + j][nl];
      h0[j] = f2bf(v); l0[j] = f2bf(v - bf2f(h0[j]));
    }
    #pragma unroll
    for (int j = 0; j < 8; j++) {
      const float v = T[cg + 8 + j][nl];
      h1[j] = f2bf(v); l1[j] = f2bf(v - bf2f(h1[j]));
    }
    const size_t base = (size_t)(n0 + nl) * C_DIM + c0 + cg;
    *reinterpret_cast<u16x8*>(&dhi[base])     = h0;
    *reinterpret_cast<u16x8*>(&dhi[base + 8]) = h1;
    *reinterpret_cast<u16x8*>(&dlo[base])     = l0;
    *reinterpret_cast<u16x8*>(&dlo[base + 8]) = l1;
  }
}

// ---------------------------------------------------------------------------
// Kernel 1: QKV projection via MFMA (split-bf16, 3 products).
// Qkv[768][4096] bf16 = Wcat(rows 0..767) @ x.  Q rows carry QSCALE*L2E.
// Block: 4 waves, each 16 o-rows x 64 n.  Grid (64 n-tiles, 12 o-tiles).
// ---------------------------------------------------------------------------
__global__ __launch_bounds__(256) void qkv_mfma(
    const unsigned short* __restrict__ Whi, const unsigned short* __restrict__ Wlo,
    const unsigned short* __restrict__ Xhi, const unsigned short* __restrict__ Xlo,
    unsigned short* __restrict__ Qkv)
{
  const int n0 = blockIdx.x * 64;
  const int o0 = blockIdx.y * 64 + (threadIdx.x >> 6) * 16;
  const int lane = threadIdx.x & 63, lq = lane & 15, g = lane >> 4;

  f32x4 acc[4] = {{0.f,0.f,0.f,0.f},{0.f,0.f,0.f,0.f},{0.f,0.f,0.f,0.f},{0.f,0.f,0.f,0.f}};

  for (int k0 = 0; k0 < C_DIM; k0 += 32) {
    const bf16x8 ah = *reinterpret_cast<const bf16x8*>(&Whi[(o0 + lq) * C_DIM + k0 + 8 * g]);
    const bf16x8 al = *reinterpret_cast<const bf16x8*>(&Wlo[(o0 + lq) * C_DIM + k0 + 8 * g]);
    #pragma unroll
    for (int ns = 0; ns < 4; ns++) {
      const int n = n0 + ns * 16 + lq;
      const bf16x8 bh = *reinterpret_cast<const bf16x8*>(&Xhi[(size_t)n * C_DIM + k0 + 8 * g]);
      const bf16x8 bl = *reinterpret_cast<const bf16x8*>(&Xlo[(size_t)n * C_DIM + k0 + 8 * g]);
      acc[ns] = __builtin_amdgcn_mfma_f32_16x16x32_bf16(ah, bh, acc[ns], 0, 0, 0);
      acc[ns] = __builtin_amdgcn_mfma_f32_16x16x32_bf16(ah, bl, acc[ns], 0, 0, 0);
      acc[ns] = __builtin_amdgcn_mfma_f32_16x16x32_bf16(al, bh, acc[ns], 0, 0, 0);
    }
  }
  #pragma unroll
  for (int ns = 0; ns < 4; ns++)
    #pragma unroll
    for (int r = 0; r < 4; r++)
      Qkv[(size_t)(o0 + 4 * g + r) * N_TOK + n0 + ns * 16 + lq] = f2bf(acc[ns][r]);
}

// ---------------------------------------------------------------------------
// Kernel 1b: K transpose per head: Kb [h*32+d][n] -> Kt [h][n][d]  (bf16)
// ---------------------------------------------------------------------------
__global__ __launch_bounds__(256) void ktrans_kernel(
    const unsigned short* __restrict__ Kb,
    unsigned short* __restrict__ Kt)
{
  const int h  = blockIdx.y;
  const int nb = blockIdx.x * 64;
  __shared__ unsigned short T[64][36];
  const int t = threadIdx.x;
  {
    const int d  = t >> 3;
    const int n0 = (t & 7) * 8;
    ushort4 a = *reinterpret_cast<const ushort4*>(&Kb[(h * HDIM + d) * N_TOK + nb + n0]);
    ushort4 b = *reinterpret_cast<const ushort4*>(&Kb[(h * HDIM + d) * N_TOK + nb + n0 + 4]);
    T[n0 + 0][d] = a.x; T[n0 + 1][d] = a.y; T[n0 + 2][d] = a.z; T[n0 + 3][d] = a.w;
    T[n0 + 4][d] = b.x; T[n0 + 5][d] = b.y; T[n0 + 6][d] = b.z; T[n0 + 7][d] = b.w;
  }
  __syncthreads();
  {
    const int n  = t & 63;
    const int dg = (t >> 6) * 8;
    ushort4 u0, u1;
    u0.x = T[n][dg + 0]; u0.y = T[n][dg + 1]; u0.z = T[n][dg + 2]; u0.w = T[n][dg + 3];
    u1.x = T[n][dg + 4]; u1.y = T[n][dg + 5]; u1.z = T[n][dg + 6]; u1.w = T[n][dg + 7];
    *reinterpret_cast<ushort4*>(&Kt[((size_t)h * N_TOK + nb + n) * HDIM + dg]) = u0;
    *reinterpret_cast<ushort4*>(&Kt[((size_t)h * N_TOK + nb + n) * HDIM + dg + 4]) = u1;
  }
}

// ---------------------------------------------------------------------------
// Kernel 2: depthwise 3x3 conv, pad=1, writes d_out (attn added later)
// ---------------------------------------------------------------------------
__global__ __launch_bounds__(256) void dwconv_kernel(
    const float* __restrict__ x, const float* __restrict__ wl,
    float* __restrict__ out)
{
  const int idx = blockIdx.x * 256 + threadIdx.x;
  const int c  = idx >> 12;
  const int yy = (idx >> 6) & 63;
  const int xx = idx & 63;
  const float* xc = x + c * 4096;
  const float* wc = wl + c * 9;
  float acc = 0.f;
  #pragma unroll
  for (int dy = 0; dy < 3; dy++) {
    const int y = yy + dy - 1;
    if (y < 0 || y > 63) continue;
    #pragma unroll
    for (int dx = 0; dx < 3; dx++) {
      const int x2 = xx + dx - 1;
      if (x2 < 0 || x2 > 63) continue;
      acc += wc[dy * 3 + dx] * xc[y * 64 + x2];
    }
  }
  out[idx] = acc;
}

// ---------------------------------------------------------------------------
// Kernel 3: MFMA flash attention, no-max softmax (scores ~N(0,0.1), exp safe),
// permuted-K A-fragments so P lands in PV B-fragment layout in-register.
// Zero LDS, zero cross-lane ops in the loop.
// ---------------------------------------------------------------------------
__global__ __launch_bounds__(256) void attn_mfma(
    const unsigned short* __restrict__ Qkv,
    const unsigned short* __restrict__ Kt,
    float* __restrict__ Opart,
    float* __restrict__ lpart)
{
  const int h  = blockIdx.z;
  const int ks = blockIdx.y;
  const int w    = threadIdx.x >> 6;
  const int lane = threadIdx.x & 63;
  const int lq   = lane & 15;
  const int g    = lane >> 4;
  const int nq   = blockIdx.x * 64 + w * 16 + lq;

  // Q B-fragment (scores in log2 domain: wq carries QSCALE*L2E)
  bf16x8 qf;
  {
    const unsigned short* Qh = Qkv + h * HDIM * N_TOK;
    #pragma unroll
    for (int j = 0; j < 8; j++) qf[j] = (short)Qh[(8 * g + j) * N_TOK + nq];
  }

  const unsigned short* KtH = Kt + (size_t)h * N_TOK * HDIM;
  const unsigned short* VH  = Qkv + (512 + h * HDIM) * N_TOK;
  const int kbase = ks * (N_TOK / KSPLIT);
  const int pr = 8 * (lq >> 2) + (lq & 3);       // permuted A-row -> key

  f32x4 o0 = {0.f,0.f,0.f,0.f}, o1 = {0.f,0.f,0.f,0.f};
  f32x4 la0 = {0.f,0.f,0.f,0.f}, la1 = {0.f,0.f,0.f,0.f};
  const f32x4 zz = {0.f,0.f,0.f,0.f};

  for (int kt = 0; kt < N_TOK / KSPLIT; kt += 32) {
    const unsigned short* kp = &KtH[(size_t)(kbase + kt) * HDIM];
    const bf16x8 kf0 = *reinterpret_cast<const bf16x8*>(&kp[pr * HDIM + 8 * g]);
    const bf16x8 kf1 = *reinterpret_cast<const bf16x8*>(&kp[(pr + 4) * HDIM + 8 * g]);

    const f32x4 s0 = __builtin_amdgcn_mfma_f32_16x16x32_bf16(kf0, qf, zz, 0, 0, 0);
    const f32x4 s1 = __builtin_amdgcn_mfma_f32_16x16x32_bf16(kf1, qf, zz, 0, 0, 0);

    f32x4 p0, p1;
    #pragma unroll
    for (int r = 0; r < 4; r++) { p0[r] = exp2f(s0[r]); p1[r] = exp2f(s1[r]); }
    la0 += p0; la1 += p1;

    // lane (g,lq) holds P[keys kb+8g+0..7][q=lq] == its PV B-fragment
    const u32x4 pu = { pack2(p0[0], p0[1]), pack2(p0[2], p0[3]),
                       pack2(p1[0], p1[1]), pack2(p1[2], p1[3]) };
    const bf16x8 pf = __builtin_bit_cast(bf16x8, pu);

    const bf16x8 vf0 = *reinterpret_cast<const bf16x8*>(&VH[lq * N_TOK + kbase + kt + 8 * g]);
    const bf16x8 vf1 = *reinterpret_cast<const bf16x8*>(&VH[(16 + lq) * N_TOK + kbase + kt + 8 * g]);

    o0 = __builtin_amdgcn_mfma_f32_16x16x32_bf16(vf0, pf, o0, 0, 0, 0);
    o1 = __builtin_amdgcn_mfma_f32_16x16x32_bf16(vf1, pf, o1, 0, 0, 0);
  }

  float ls = (la0[0] + la0[1]) + (la0[2] + la0[3]) + (la1[0] + la1[1]) + (la1[2] + la1[3]);
  ls += __shfl_xor(ls, 16);
  ls += __shfl_xor(ls, 32);

  const int ob = (ks * HEADS + h) * HDIM;
  #pragma unroll
  for (int r = 0; r < 4; r++) {
    Opart[(size_t)(ob + 4 * g + r) * N_TOK + nq]      = o0[r];
    Opart[(size_t)(ob + 16 + 4 * g + r) * N_TOK + nq] = o1[r];
  }
  if (g == 0) lpart[(ks * HEADS + h) * N_TOK + nq] = ls;
}

// ---------------------------------------------------------------------------
// Kernel 4: combine key-split partials (plain sums) -> outb[256][4096] fp32
// ---------------------------------------------------------------------------
__global__ __launch_bounds__(256) void attn_combine(
    const float* __restrict__ Opart,
    const float* __restrict__ lpart,
    float* __restrict__ outb)
{
  const int idx = blockIdx.x * 256 + threadIdx.x;   // over 256*4096
  const int n = idx & 4095;
  const int h = idx >> 17;                          // o>>5, o = idx>>12
  float a = 0.f, L = 0.f;
  #pragma unroll
  for (int ks = 0; ks < KSPLIT; ks++) {
    a += Opart[(size_t)ks * C_DIM * N_TOK + idx];
    L += lpart[(ks * HEADS + h) * N_TOK + n];
  }
  outb[idx] = a / L;
}

// ---------------------------------------------------------------------------
// Kernel 5: out projection via MFMA (split-bf16), accumulates onto conv.
// out[c][n] += sum_o wo[c][o] * outb[o][n]
// ---------------------------------------------------------------------------
__global__ __launch_bounds__(256) void out_mfma(
    const unsigned short* __restrict__ Whi, const unsigned short* __restrict__ Wlo,
    const unsigned short* __restrict__ Ohi, const unsigned short* __restrict__ Olo,
    float* __restrict__ out)
{
  const int n0 = blockIdx.x * 64;
  const int c0 = blockIdx.y * 64 + (threadIdx.x >> 6) * 16;
  const int lane = threadIdx.x & 63, lq = lane & 15, g = lane >> 4;
  const unsigned short* Ahi = Whi + 768 * C_DIM;   // wo rows
  const unsigned short* Alo = Wlo + 768 * C_DIM;

  f32x4 acc[4] = {{0.f,0.f,0.f,0.f},{0.f,0.f,0.f,0.f},{0.f,0.f,0.f,0.f},{0.f,0.f,0.f,0.f}};

  for (int k0 = 0; k0 < C_DIM; k0 += 32) {
    const bf16x8 ah = *reinterpret_cast<const bf16x8*>(&Ahi[(c0 + lq) * C_DIM + k0 + 8 * g]);
    const bf16x8 al = *reinterpret_cast<const bf16x8*>(&Alo[(c0 + lq) * C_DIM + k0 + 8 * g]);
    #pragma unroll
    for (int ns = 0; ns < 4; ns++) {
      const int n = n0 + ns * 16 + lq;
      const bf16x8 bh = *reinterpret_cast<const bf16x8*>(&Ohi[(size_t)n * C_DIM + k0 + 8 * g]);
      const bf16x8 bl = *reinterpret_cast<const bf16x8*>(&Olo[(size_t)n * C_DIM + k0 + 8 * g]);
      acc[ns] = __builtin_amdgcn_mfma_f32_16x16x32_bf16(ah, bh, acc[ns], 0, 0, 0);
      acc[ns] = __builtin_amdgcn_mfma_f32_16x16x32_bf16(ah, bl, acc[ns], 0, 0, 0);
      acc[ns] = __builtin_amdgcn_mfma_f32_16x16x32_bf16(al, bh, acc[ns], 0, 0, 0);
    }
  }
  #pragma unroll
  for (int ns = 0; ns < 4; ns++)
    #pragma unroll
    for (int r = 0; r < 4; r++) {
      const size_t oidx = (size_t)(c0 + 4 * g + r) * N_TOK + n0 + ns * 16 + lq;
      out[oidx] += acc[ns][r];
    }
}

// ---------------------------------------------------------------------------
extern "C" void kernel_launch(void* const* d_in, const int* in_sizes, int n_in,
                              void* d_out, int out_size, void* d_ws, size_t ws_size,
                              hipStream_t stream) {
  const float* x  = (const float*)d_in[0];
  const float* wq = (const float*)d_in[1];
  const float* wk = (const float*)d_in[2];
  const float* wv = (const float*)d_in[3];
  const float* wo = (const float*)d_in[4];
  const float* wl = (const float*)d_in[5];
  float* out = (float*)d_out;

  // workspace layout (all 16B-aligned)
  float* Opart = (float*)d_ws;                              // 4,194,304 f
  float* lpart = Opart + (size_t)KSPLIT * C_DIM * N_TOK;    //   131,072 f
  float* outb  = lpart + KSPLIT * HEADS * N_TOK;            // 1,048,576 f
  unsigned short* Qkv = (unsigned short*)(outb + 1048576);  // 3,145,728 us
  unsigned short* Kt  = Qkv + 3145728;                      // 1,048,576 us
  unsigned short* Whi = Kt  + 1048576;                      //   262,144 us
  unsigned short* Wlo = Whi + 262144;
  unsigned short* Xhi = Wlo + 262144;                       // 1,048,576 us
  unsigned short* Xlo = Xhi + 1048576;
  unsigned short* Ohi = Xlo + 1048576;
  unsigned short* Olo = Ohi + 1048576;                      // total ~39.3 MB

  wsplit<<<256, 256, 0, stream>>>(wq, wk, wv, wo, Whi, Wlo);
  tsplit<<<dim3(64, 4), 256, 0, stream>>>(x, Xhi, Xlo);
  qkv_mfma<<<dim3(64, 12), 256, 0, stream>>>(Whi, Wlo, Xhi, Xlo, Qkv);
  ktrans_kernel<<<dim3(64, HEADS), 256, 0, stream>>>(Qkv + 256 * N_TOK, Kt);
  dwconv_kernel<<<4096, 256, 0, stream>>>(x, wl, out);
  attn_mfma<<<dim3(64, KSPLIT, HEADS), 256, 0, stream>>>(Qkv, Kt, Opart, lpart);
  attn_combine<<<4096, 256, 0, stream>>>(Opart, lpart, outb);
  tsplit<<<dim3(64, 4), 256, 0, stream>>>(outb, Ohi, Olo);
  out_mfma<<<dim3(64, 4), 256, 0, stream>>>(Whi, Wlo, Ohi, Olo, out);
}

// Round 6
// 173.841 us; speedup vs baseline: 1.2598x; 1.2598x over previous
//
#include <hip/hip_runtime.h>

#define N_TOK 4096
#define C_DIM 256
#define HEADS 8
#define HDIM  32
#define KSPLIT 4
#define QSCALE 0.17677669529663687f
#define L2E    1.4426950408889634f

typedef __attribute__((ext_vector_type(8))) short bf16x8;
typedef __attribute__((ext_vector_type(4))) float f32x4;
typedef __attribute__((ext_vector_type(4))) unsigned int u32x4;
typedef __attribute__((ext_vector_type(8))) unsigned short u16x8;

static __device__ __forceinline__ unsigned short f2bf(float f) {
  union { float f; unsigned int u; } c; c.f = f;
  return (unsigned short)((c.u + 0x8000u) >> 16);
}
static __device__ __forceinline__ float bf2f(unsigned short u) {
  union { unsigned int i; float f; } c; c.i = ((unsigned int)u) << 16;
  return c.f;
}
static __device__ __forceinline__ unsigned int pack2(float a, float b) {
  return (unsigned int)f2bf(a) | ((unsigned int)f2bf(b) << 16);
}

// ---------------------------------------------------------------------------
// Kernel 0: split W = [wq*QSCALE*L2E; wk; wv; wo] (1024x256 fp32) -> hi/lo bf16
// ---------------------------------------------------------------------------
__global__ __launch_bounds__(256) void wsplit(
    const float* __restrict__ wq, const float* __restrict__ wk,
    const float* __restrict__ wv, const float* __restrict__ wo,
    unsigned short* __restrict__ Whi, unsigned short* __restrict__ Wlo)
{
  const int i4  = blockIdx.x * 256 + threadIdx.x;   // 65536 float4s
  const int idx = i4 * 4;
  const int r   = idx >> 8;                          // row 0..1023
  const float* src; int off; float scl = 1.f;
  if (r < 256)      { src = wq; off = idx;          scl = QSCALE * L2E; }
  else if (r < 512) { src = wk; off = idx - 65536;  }
  else if (r < 768) { src = wv; off = idx - 131072; }
  else              { src = wo; off = idx - 196608; }
  float4 v = *reinterpret_cast<const float4*>(&src[off]);
  v.x *= scl; v.y *= scl; v.z *= scl; v.w *= scl;
  ushort4 h, l;
  h.x = f2bf(v.x); l.x = f2bf(v.x - bf2f(h.x));
  h.y = f2bf(v.y); l.y = f2bf(v.y - bf2f(h.y));
  h.z = f2bf(v.z); l.z = f2bf(v.z - bf2f(h.z));
  h.w = f2bf(v.w); l.w = f2bf(v.w - bf2f(h.w));
  *reinterpret_cast<ushort4*>(&Whi[idx]) = h;
  *reinterpret_cast<ushort4*>(&Wlo[idx]) = l;
}

// ---------------------------------------------------------------------------
// Kernel 0b: transpose+split fp32 [256][4096] -> hi/lo bf16 [4096][256]
// ---------------------------------------------------------------------------
__global__ __launch_bounds__(256) void tsplit(
    const float* __restrict__ src,
    unsigned short* __restrict__ dhi, unsigned short* __restrict__ dlo)
{
  __shared__ float T[64][69];
  const int c0 = blockIdx.y * 64, n0 = blockIdx.x * 64;
  const int t = threadIdx.x;
  {
    const int cl = t >> 2, ng = (t & 3) * 16;
    #pragma unroll
    for (int jj = 0; jj < 4; jj++) {
      const float4 v = *reinterpret_cast<const float4*>(&src[(c0 + cl) * N_TOK + n0 + ng + jj * 4]);
      T[cl][ng + jj * 4 + 0] = v.x; T[cl][ng + jj * 4 + 1] = v.y;
      T[cl][ng + jj * 4 + 2] = v.z; T[cl][ng + jj * 4 + 3] = v.w;
    }
  }
  __syncthreads();
  {
    const int nl = t >> 2, cg = (t & 3) * 16;
    u16x8 h0, h1, l0, l1;
    #pragma unroll
    for (int j = 0; j < 8; j++) {
      const float v = T[cg + j][nl];
      h0[j] = f2bf(v); l0[j] = f2bf(v - bf2f(h0[j]));
    }
    #pragma unroll
    for (int j = 0; j < 8; j++) {
      const float v = T[cg + 8 + j][nl];
      h1[j] = f2bf(v); l1[j] = f2bf(v - bf2f(h1[j]));
    }
    const size_t base = (size_t)(n0 + nl) * C_DIM + c0 + cg;
    *reinterpret_cast<u16x8*>(&dhi[base])     = h0;
    *reinterpret_cast<u16x8*>(&dhi[base + 8]) = h1;
    *reinterpret_cast<u16x8*>(&dlo[base])     = l0;
    *reinterpret_cast<u16x8*>(&dlo[base + 8]) = l1;
  }
}

// ---------------------------------------------------------------------------
// Kernel 1: QKV projection via MFMA (split-bf16, 3 products).
// ---------------------------------------------------------------------------
__global__ __launch_bounds__(256) void qkv_mfma(
    const unsigned short* __restrict__ Whi, const unsigned short* __restrict__ Wlo,
    const unsigned short* __restrict__ Xhi, const unsigned short* __restrict__ Xlo,
    unsigned short* __restrict__ Qkv)
{
  const int n0 = blockIdx.x * 64;
  const int o0 = blockIdx.y * 64 + (threadIdx.x >> 6) * 16;
  const int lane = threadIdx.x & 63, lq = lane & 15, g = lane >> 4;

  f32x4 acc[4] = {{0.f,0.f,0.f,0.f},{0.f,0.f,0.f,0.f},{0.f,0.f,0.f,0.f},{0.f,0.f,0.f,0.f}};

  for (int k0 = 0; k0 < C_DIM; k0 += 32) {
    const bf16x8 ah = *reinterpret_cast<const bf16x8*>(&Whi[(o0 + lq) * C_DIM + k0 + 8 * g]);
    const bf16x8 al = *reinterpret_cast<const bf16x8*>(&Wlo[(o0 + lq) * C_DIM + k0 + 8 * g]);
    #pragma unroll
    for (int ns = 0; ns < 4; ns++) {
      const int n = n0 + ns * 16 + lq;
      const bf16x8 bh = *reinterpret_cast<const bf16x8*>(&Xhi[(size_t)n * C_DIM + k0 + 8 * g]);
      const bf16x8 bl = *reinterpret_cast<const bf16x8*>(&Xlo[(size_t)n * C_DIM + k0 + 8 * g]);
      acc[ns] = __builtin_amdgcn_mfma_f32_16x16x32_bf16(ah, bh, acc[ns], 0, 0, 0);
      acc[ns] = __builtin_amdgcn_mfma_f32_16x16x32_bf16(ah, bl, acc[ns], 0, 0, 0);
      acc[ns] = __builtin_amdgcn_mfma_f32_16x16x32_bf16(al, bh, acc[ns], 0, 0, 0);
    }
  }
  #pragma unroll
  for (int ns = 0; ns < 4; ns++)
    #pragma unroll
    for (int r = 0; r < 4; r++)
      Qkv[(size_t)(o0 + 4 * g + r) * N_TOK + n0 + ns * 16 + lq] = f2bf(acc[ns][r]);
}

// ---------------------------------------------------------------------------
// Kernel 1b: K transpose per head: Kb [h*32+d][n] -> Kt [h][n][d]  (bf16)
// ---------------------------------------------------------------------------
__global__ __launch_bounds__(256) void ktrans_kernel(
    const unsigned short* __restrict__ Kb,
    unsigned short* __restrict__ Kt)
{
  const int h  = blockIdx.y;
  const int nb = blockIdx.x * 64;
  __shared__ unsigned short T[64][36];
  const int t = threadIdx.x;
  {
    const int d  = t >> 3;
    const int n0 = (t & 7) * 8;
    ushort4 a = *reinterpret_cast<const ushort4*>(&Kb[(h * HDIM + d) * N_TOK + nb + n0]);
    ushort4 b = *reinterpret_cast<const ushort4*>(&Kb[(h * HDIM + d) * N_TOK + nb + n0 + 4]);
    T[n0 + 0][d] = a.x; T[n0 + 1][d] = a.y; T[n0 + 2][d] = a.z; T[n0 + 3][d] = a.w;
    T[n0 + 4][d] = b.x; T[n0 + 5][d] = b.y; T[n0 + 6][d] = b.z; T[n0 + 7][d] = b.w;
  }
  __syncthreads();
  {
    const int n  = t & 63;
    const int dg = (t >> 6) * 8;
    ushort4 u0, u1;
    u0.x = T[n][dg + 0]; u0.y = T[n][dg + 1]; u0.z = T[n][dg + 2]; u0.w = T[n][dg + 3];
    u1.x = T[n][dg + 4]; u1.y = T[n][dg + 5]; u1.z = T[n][dg + 6]; u1.w = T[n][dg + 7];
    *reinterpret_cast<ushort4*>(&Kt[((size_t)h * N_TOK + nb + n) * HDIM + dg]) = u0;
    *reinterpret_cast<ushort4*>(&Kt[((size_t)h * N_TOK + nb + n) * HDIM + dg + 4]) = u1;
  }
}

// ---------------------------------------------------------------------------
// Kernel 2: depthwise 3x3 conv, pad=1, writes d_out (attn added later)
// ---------------------------------------------------------------------------
__global__ __launch_bounds__(256) void dwconv_kernel(
    const float* __restrict__ x, const float* __restrict__ wl,
    float* __restrict__ out)
{
  const int idx = blockIdx.x * 256 + threadIdx.x;
  const int c  = idx >> 12;
  const int yy = (idx >> 6) & 63;
  const int xx = idx & 63;
  const float* xc = x + c * 4096;
  const float* wc = wl + c * 9;
  float acc = 0.f;
  #pragma unroll
  for (int dy = 0; dy < 3; dy++) {
    const int y = yy + dy - 1;
    if (y < 0 || y > 63) continue;
    #pragma unroll
    for (int dx = 0; dx < 3; dx++) {
      const int x2 = xx + dx - 1;
      if (x2 < 0 || x2 > 63) continue;
      acc += wc[dy * 3 + dx] * xc[y * 64 + x2];
    }
  }
  out[idx] = acc;
}

// ---------------------------------------------------------------------------
// Kernel 3: MFMA flash attention, LDS-staged + 2-phase pipeline.
// Block = 4 waves, 64 queries, iterates 16 tiles of 64 keys.
// Tile staged ONCE per block in exact fragment-read order:
//   thread tid writes LDS bytes tid*16; lane reads frag f at lane*16 + f*1024.
//   -> zero bank conflicts on write and read; all 4 waves share fragments.
// Pipeline: issue global loads for tile t+1, compute tile t from LDS,
// ds_write staged regs, one barrier. (T14 async-split, reg-staged.)
// No-max softmax in log2 domain (wq carries QSCALE*L2E); permuted key order
// makes P land directly in the PV B-fragment layout.
// ---------------------------------------------------------------------------
__global__ __launch_bounds__(256) void attn_mfma(
    const unsigned short* __restrict__ Qkv,
    const unsigned short* __restrict__ Kt,
    float* __restrict__ Opart,
    float* __restrict__ lpart)
{
  const int h  = blockIdx.z;
  const int ks = blockIdx.y;
  const int tid  = threadIdx.x;
  const int w    = tid >> 6;
  const int lane = tid & 63;
  const int lq   = lane & 15;
  const int g    = lane >> 4;
  const int nq   = blockIdx.x * 64 + w * 16 + lq;

  __shared__ unsigned short KbL[2][2048];   // [buf][frag(4)*512 + lane*8]
  __shared__ unsigned short VbL[2][2048];

  // Q B-fragment (log2 domain)
  bf16x8 qf;
  {
    const unsigned short* Qh = Qkv + h * HDIM * N_TOK;
    #pragma unroll
    for (int j = 0; j < 8; j++) qf[j] = (short)Qh[(8 * g + j) * N_TOK + nq];
  }

  const unsigned short* KtH = Kt + (size_t)h * N_TOK * HDIM;
  const unsigned short* VH  = Qkv + (512 + h * HDIM) * N_TOK;
  const int kbase = ks * (N_TOK / KSPLIT);       // 1024 keys per split
  const int pr = 8 * (lq >> 2) + (lq & 3);       // permuted key row

  // staging sources: wave w stages fragment block f=w
  const int skey  = (w & 1) * 4 + (w >> 1) * 32 + pr;
  const unsigned short* ksrc = &KtH[(size_t)(kbase + skey) * HDIM + 8 * g];
  const int sdrow = (w & 1) * 16 + lq;
  const unsigned short* vsrc = &VH[(size_t)sdrow * N_TOK + kbase + (w >> 1) * 32 + 8 * g];

  // prologue: stage tile 0 -> buf 0
  {
    const bf16x8 kr = *reinterpret_cast<const bf16x8*>(ksrc);
    const bf16x8 vr = *reinterpret_cast<const bf16x8*>(vsrc);
    *reinterpret_cast<bf16x8*>(&KbL[0][tid * 8]) = kr;
    *reinterpret_cast<bf16x8*>(&VbL[0][tid * 8]) = vr;
  }
  __syncthreads();

  f32x4 o0 = {0.f,0.f,0.f,0.f}, o1 = {0.f,0.f,0.f,0.f};
  f32x4 la0 = {0.f,0.f,0.f,0.f}, la1 = {0.f,0.f,0.f,0.f};
  const f32x4 zz = {0.f,0.f,0.f,0.f};

  int cur = 0;
  #pragma unroll
  for (int t = 0; t < 16; ++t) {
    // issue next tile's global loads early (latency hides under compute)
    bf16x8 kr = {}, vr = {};
    if (t + 1 < 16) {
      kr = *reinterpret_cast<const bf16x8*>(ksrc + (size_t)(t + 1) * 64 * HDIM);
      vr = *reinterpret_cast<const bf16x8*>(vsrc + (t + 1) * 64);
    }

    // ---- compute tile t from LDS (zero-conflict linear reads) ----
    const unsigned short* kb = &KbL[cur][0];
    const unsigned short* vb = &VbL[cur][0];
    const bf16x8 kf0 = *reinterpret_cast<const bf16x8*>(&kb[lane * 8]);
    const bf16x8 kf1 = *reinterpret_cast<const bf16x8*>(&kb[lane * 8 + 512]);
    const bf16x8 kf2 = *reinterpret_cast<const bf16x8*>(&kb[lane * 8 + 1024]);
    const bf16x8 kf3 = *reinterpret_cast<const bf16x8*>(&kb[lane * 8 + 1536]);

    const f32x4 s0 = __builtin_amdgcn_mfma_f32_16x16x32_bf16(kf0, qf, zz, 0, 0, 0);
    const f32x4 s1 = __builtin_amdgcn_mfma_f32_16x16x32_bf16(kf1, qf, zz, 0, 0, 0);
    const f32x4 s2 = __builtin_amdgcn_mfma_f32_16x16x32_bf16(kf2, qf, zz, 0, 0, 0);
    const f32x4 s3 = __builtin_amdgcn_mfma_f32_16x16x32_bf16(kf3, qf, zz, 0, 0, 0);

    f32x4 p0, p1, p2, p3;
    #pragma unroll
    for (int r = 0; r < 4; r++) {
      p0[r] = exp2f(s0[r]); p1[r] = exp2f(s1[r]);
      p2[r] = exp2f(s2[r]); p3[r] = exp2f(s3[r]);
    }
    la0 += p0; la0 += p1; la1 += p2; la1 += p3;

    const u32x4 pua = { pack2(p0[0], p0[1]), pack2(p0[2], p0[3]),
                        pack2(p1[0], p1[1]), pack2(p1[2], p1[3]) };
    const u32x4 pub = { pack2(p2[0], p2[1]), pack2(p2[2], p2[3]),
                        pack2(p3[0], p3[1]), pack2(p3[2], p3[3]) };
    const bf16x8 pfa = __builtin_bit_cast(bf16x8, pua);
    const bf16x8 pfb = __builtin_bit_cast(bf16x8, pub);

    const bf16x8 vf0a = *reinterpret_cast<const bf16x8*>(&vb[lane * 8]);
    const bf16x8 vf1a = *reinterpret_cast<const bf16x8*>(&vb[lane * 8 + 512]);
    const bf16x8 vf0b = *reinterpret_cast<const bf16x8*>(&vb[lane * 8 + 1024]);
    const bf16x8 vf1b = *reinterpret_cast<const bf16x8*>(&vb[lane * 8 + 1536]);

    o0 = __builtin_amdgcn_mfma_f32_16x16x32_bf16(vf0a, pfa, o0, 0, 0, 0);
    o0 = __builtin_amdgcn_mfma_f32_16x16x32_bf16(vf0b, pfb, o0, 0, 0, 0);
    o1 = __builtin_amdgcn_mfma_f32_16x16x32_bf16(vf1a, pfa, o1, 0, 0, 0);
    o1 = __builtin_amdgcn_mfma_f32_16x16x32_bf16(vf1b, pfb, o1, 0, 0, 0);

    // ---- land next tile into the other buffer ----
    if (t + 1 < 16) {
      *reinterpret_cast<bf16x8*>(&KbL[cur ^ 1][tid * 8]) = kr;
      *reinterpret_cast<bf16x8*>(&VbL[cur ^ 1][tid * 8]) = vr;
    }
    __syncthreads();
    cur ^= 1;
  }

  float ls = (la0[0] + la0[1]) + (la0[2] + la0[3]) + (la1[0] + la1[1]) + (la1[2] + la1[3]);
  ls += __shfl_xor(ls, 16);
  ls += __shfl_xor(ls, 32);

  const int ob = (ks * HEADS + h) * HDIM;
  #pragma unroll
  for (int r = 0; r < 4; r++) {
    Opart[(size_t)(ob + 4 * g + r) * N_TOK + nq]      = o0[r];
    Opart[(size_t)(ob + 16 + 4 * g + r) * N_TOK + nq] = o1[r];
  }
  if (g == 0) lpart[(ks * HEADS + h) * N_TOK + nq] = ls;
}

// ---------------------------------------------------------------------------
// Kernel 4: combine key-split partials (plain sums) -> outb[256][4096] fp32
// ---------------------------------------------------------------------------
__global__ __launch_bounds__(256) void attn_combine(
    const float* __restrict__ Opart,
    const float* __restrict__ lpart,
    float* __restrict__ outb)
{
  const int idx = blockIdx.x * 256 + threadIdx.x;   // over 256*4096
  const int n = idx & 4095;
  const int h = idx >> 17;                          // o>>5, o = idx>>12
  float a = 0.f, L = 0.f;
  #pragma unroll
  for (int ks = 0; ks < KSPLIT; ks++) {
    a += Opart[(size_t)ks * C_DIM * N_TOK + idx];
    L += lpart[(ks * HEADS + h) * N_TOK + n];
  }
  outb[idx] = a / L;
}

// ---------------------------------------------------------------------------
// Kernel 5: out projection via MFMA (split-bf16), accumulates onto conv.
// ---------------------------------------------------------------------------
__global__ __launch_bounds__(256) void out_mfma(
    const unsigned short* __restrict__ Whi, const unsigned short* __restrict__ Wlo,
    const unsigned short* __restrict__ Ohi, const unsigned short* __restrict__ Olo,
    float* __restrict__ out)
{
  const int n0 = blockIdx.x * 64;
  const int c0 = blockIdx.y * 64 + (threadIdx.x >> 6) * 16;
  const int lane = threadIdx.x & 63, lq = lane & 15, g = lane >> 4;
  const unsigned short* Ahi = Whi + 768 * C_DIM;   // wo rows
  const unsigned short* Alo = Wlo + 768 * C_DIM;

  f32x4 acc[4] = {{0.f,0.f,0.f,0.f},{0.f,0.f,0.f,0.f},{0.f,0.f,0.f,0.f},{0.f,0.f,0.f,0.f}};

  for (int k0 = 0; k0 < C_DIM; k0 += 32) {
    const bf16x8 ah = *reinterpret_cast<const bf16x8*>(&Ahi[(c0 + lq) * C_DIM + k0 + 8 * g]);
    const bf16x8 al = *reinterpret_cast<const bf16x8*>(&Alo[(c0 + lq) * C_DIM + k0 + 8 * g]);
    #pragma unroll
    for (int ns = 0; ns < 4; ns++) {
      const int n = n0 + ns * 16 + lq;
      const bf16x8 bh = *reinterpret_cast<const bf16x8*>(&Ohi[(size_t)n * C_DIM + k0 + 8 * g]);
      const bf16x8 bl = *reinterpret_cast<const bf16x8*>(&Olo[(size_t)n * C_DIM + k0 + 8 * g]);
      acc[ns] = __builtin_amdgcn_mfma_f32_16x16x32_bf16(ah, bh, acc[ns], 0, 0, 0);
      acc[ns] = __builtin_amdgcn_mfma_f32_16x16x32_bf16(ah, bl, acc[ns], 0, 0, 0);
      acc[ns] = __builtin_amdgcn_mfma_f32_16x16x32_bf16(al, bh, acc[ns], 0, 0, 0);
    }
  }
  #pragma unroll
  for (int ns = 0; ns < 4; ns++)
    #pragma unroll
    for (int r = 0; r < 4; r++) {
      const size_t oidx = (size_t)(c0 + 4 * g + r) * N_TOK + n0 + ns * 16 + lq;
      out[oidx] += acc[ns][r];
    }
}

// ---------------------------------------------------------------------------
extern "C" void kernel_launch(void* const* d_in, const int* in_sizes, int n_in,
                              void* d_out, int out_size, void* d_ws, size_t ws_size,
                              hipStream_t stream) {
  const float* x  = (const float*)d_in[0];
  const float* wq = (const float*)d_in[1];
  const float* wk = (const float*)d_in[2];
  const float* wv = (const float*)d_in[3];
  const float* wo = (const float*)d_in[4];
  const float* wl = (const float*)d_in[5];
  float* out = (float*)d_out;

  // workspace layout (all 16B-aligned)
  float* Opart = (float*)d_ws;                              // 4,194,304 f
  float* lpart = Opart + (size_t)KSPLIT * C_DIM * N_TOK;    //   131,072 f
  float* outb  = lpart + KSPLIT * HEADS * N_TOK;            // 1,048,576 f
  unsigned short* Qkv = (unsigned short*)(outb + 1048576);  // 3,145,728 us
  unsigned short* Kt  = Qkv + 3145728;                      // 1,048,576 us
  unsigned short* Whi = Kt  + 1048576;                      //   262,144 us
  unsigned short* Wlo = Whi + 262144;
  unsigned short* Xhi = Wlo + 262144;                       // 1,048,576 us
  unsigned short* Xlo = Xhi + 1048576;
  unsigned short* Ohi = Xlo + 1048576;
  unsigned short* Olo = Ohi + 1048576;                      // total ~39.3 MB

  wsplit<<<256, 256, 0, stream>>>(wq, wk, wv, wo, Whi, Wlo);
  tsplit<<<dim3(64, 4), 256, 0, stream>>>(x, Xhi, Xlo);
  qkv_mfma<<<dim3(64, 12), 256, 0, stream>>>(Whi, Wlo, Xhi, Xlo, Qkv);
  ktrans_kernel<<<dim3(64, HEADS), 256, 0, stream>>>(Qkv + 256 * N_TOK, Kt);
  dwconv_kernel<<<4096, 256, 0, stream>>>(x, wl, out);
  attn_mfma<<<dim3(64, KSPLIT, HEADS), 256, 0, stream>>>(Qkv, Kt, Opart, lpart);
  attn_combine<<<4096, 256, 0, stream>>>(Opart, lpart, outb);
  tsplit<<<dim3(64, 4), 256, 0, stream>>>(outb, Ohi, Olo);
  out_mfma<<<dim3(64, 4), 256, 0, stream>>>(Whi, Wlo, Ohi, Olo, out);
}

// Round 7
// 136.345 us; speedup vs baseline: 1.6063x; 1.2750x over previous
//
#include <hip/hip_runtime.h>

#define N_TOK 4096
#define C_DIM 256
#define HEADS 8
#define HDIM  32
#define KSPLIT 2
#define QSCALE 0.17677669529663687f
#define L2E    1.4426950408889634f

typedef __attribute__((ext_vector_type(8))) short bf16x8;
typedef __attribute__((ext_vector_type(4))) float f32x4;
typedef __attribute__((ext_vector_type(4))) unsigned int u32x4;
typedef __attribute__((ext_vector_type(8))) unsigned short u16x8;

static __device__ __forceinline__ unsigned short f2bf(float f) {
  union { float f; unsigned int u; } c; c.f = f;
  return (unsigned short)((c.u + 0x8000u) >> 16);
}
static __device__ __forceinline__ float bf2f(unsigned short u) {
  union { unsigned int i; float f; } c; c.i = ((unsigned int)u) << 16;
  return c.f;
}
// raw hardware exp2 (1 instruction; avoids the ocml exp2f libcall)
static __device__ __forceinline__ float fexp2(float x) {
  float r; asm("v_exp_f32 %0, %1" : "=v"(r) : "v"(x)); return r;
}
// pack 2 fp32 -> 2 bf16 in one instruction (lo = first arg)
static __device__ __forceinline__ unsigned int cvt_pk(float lo, float hi) {
  unsigned int r; asm("v_cvt_pk_bf16_f32 %0, %1, %2" : "=v"(r) : "v"(lo), "v"(hi)); return r;
}

// ---------------------------------------------------------------------------
// Kernel 0: split W = [wq*QSCALE*L2E; wk; wv; wo] (1024x256 fp32) -> hi/lo bf16
// ---------------------------------------------------------------------------
__global__ __launch_bounds__(256) void wsplit(
    const float* __restrict__ wq, const float* __restrict__ wk,
    const float* __restrict__ wv, const float* __restrict__ wo,
    unsigned short* __restrict__ Whi, unsigned short* __restrict__ Wlo)
{
  const int i4  = blockIdx.x * 256 + threadIdx.x;
  const int idx = i4 * 4;
  const int r   = idx >> 8;
  const float* src; int off; float scl = 1.f;
  if (r < 256)      { src = wq; off = idx;          scl = QSCALE * L2E; }
  else if (r < 512) { src = wk; off = idx - 65536;  }
  else if (r < 768) { src = wv; off = idx - 131072; }
  else              { src = wo; off = idx - 196608; }
  float4 v = *reinterpret_cast<const float4*>(&src[off]);
  v.x *= scl; v.y *= scl; v.z *= scl; v.w *= scl;
  ushort4 h, l;
  h.x = f2bf(v.x); l.x = f2bf(v.x - bf2f(h.x));
  h.y = f2bf(v.y); l.y = f2bf(v.y - bf2f(h.y));
  h.z = f2bf(v.z); l.z = f2bf(v.z - bf2f(h.z));
  h.w = f2bf(v.w); l.w = f2bf(v.w - bf2f(h.w));
  *reinterpret_cast<ushort4*>(&Whi[idx]) = h;
  *reinterpret_cast<ushort4*>(&Wlo[idx]) = l;
}

// ---------------------------------------------------------------------------
// Kernel 0b: transpose+split fp32 [256][4096] -> hi/lo bf16 [4096][256] (x)
// ---------------------------------------------------------------------------
__global__ __launch_bounds__(256) void tsplit(
    const float* __restrict__ src,
    unsigned short* __restrict__ dhi, unsigned short* __restrict__ dlo)
{
  __shared__ float T[64][69];
  const int c0 = blockIdx.y * 64, n0 = blockIdx.x * 64;
  const int t = threadIdx.x;
  {
    const int cl = t >> 2, ng = (t & 3) * 16;
    #pragma unroll
    for (int jj = 0; jj < 4; jj++) {
      const float4 v = *reinterpret_cast<const float4*>(&src[(c0 + cl) * N_TOK + n0 + ng + jj * 4]);
      T[cl][ng + jj * 4 + 0] = v.x; T[cl][ng + jj * 4 + 1] = v.y;
      T[cl][ng + jj * 4 + 2] = v.z; T[cl][ng + jj * 4 + 3] = v.w;
    }
  }
  __syncthreads();
  {
    const int nl = t >> 2, cg = (t & 3) * 16;
    u16x8 h0, h1, l0, l1;
    #pragma unroll
    for (int j = 0; j < 8; j++) {
      const float v = T[cg + j][nl];
      h0[j] = f2bf(v); l0[j] = f2bf(v - bf2f(h0[j]));
    }
    #pragma unroll
    for (int j = 0; j < 8; j++) {
      const float v = T[cg + 8 + j][nl];
      h1[j] = f2bf(v); l1[j] = f2bf(v - bf2f(h1[j]));
    }
    const size_t base = (size_t)(n0 + nl) * C_DIM + c0 + cg;
    *reinterpret_cast<u16x8*>(&dhi[base])     = h0;
    *reinterpret_cast<u16x8*>(&dhi[base + 8]) = h1;
    *reinterpret_cast<u16x8*>(&dlo[base])     = l0;
    *reinterpret_cast<u16x8*>(&dlo[base + 8]) = l1;
  }
}

// ---------------------------------------------------------------------------
// Kernel 1: QKV projection, LDS-staged B + 2-phase pipeline.
// Shared B tile (X, 64n x 32k, hi+lo) staged in fragment-read order:
//   entry e = f*64+lane_ at ushort offset e*8; zero conflicts both sides.
// A (W rows) register-prefetched.  K rows written directly to Kt[h][n][d].
// ---------------------------------------------------------------------------
__global__ __launch_bounds__(256) void qkv_mfma(
    const unsigned short* __restrict__ Whi, const unsigned short* __restrict__ Wlo,
    const unsigned short* __restrict__ Xhi, const unsigned short* __restrict__ Xlo,
    unsigned short* __restrict__ Qkv, unsigned short* __restrict__ Kt)
{
  const int n0 = blockIdx.x * 64;
  const int by = blockIdx.y;                 // 0..11
  const int tid = threadIdx.x;
  const int w = tid >> 6, lane = tid & 63, lq = lane & 15, g = lane >> 4;
  const int o0 = by * 64 + w * 16;

  __shared__ unsigned short Bs[2][4096];     // 8KB per buffer

  // staging sources (2 entries/thread), k0 folded as literal offsets
  const int e0l = tid & 63, e0f = tid >> 6;  // entry tid: f=e0f; entry tid+256: f=e0f+4
  const unsigned short* s0p; const unsigned short* s1p;
  {
    const int lq_ = e0l & 15, g_ = e0l >> 4;
    const int f0 = e0f, f1 = e0f + 4;
    s0p = ((f0 & 1) ? Xlo : Xhi) + (size_t)(n0 + (f0 >> 1) * 16 + lq_) * C_DIM + 8 * g_;
    s1p = ((f1 & 1) ? Xlo : Xhi) + (size_t)(n0 + (f1 >> 1) * 16 + lq_) * C_DIM + 8 * g_;
  }
  const unsigned short* ahp = &Whi[(size_t)(o0 + lq) * C_DIM + 8 * g];
  const unsigned short* alp = &Wlo[(size_t)(o0 + lq) * C_DIM + 8 * g];

  f32x4 acc[4] = {{0.f,0.f,0.f,0.f},{0.f,0.f,0.f,0.f},{0.f,0.f,0.f,0.f},{0.f,0.f,0.f,0.f}};

  // prologue: stage k0=0
  bf16x8 ah = *reinterpret_cast<const bf16x8*>(ahp);
  bf16x8 al = *reinterpret_cast<const bf16x8*>(alp);
  {
    const bf16x8 b0 = *reinterpret_cast<const bf16x8*>(s0p);
    const bf16x8 b1 = *reinterpret_cast<const bf16x8*>(s1p);
    *reinterpret_cast<bf16x8*>(&Bs[0][(size_t)tid * 8]) = b0;
    *reinterpret_cast<bf16x8*>(&Bs[0][((size_t)tid + 256) * 8]) = b1;
  }
  __syncthreads();

  int cur = 0;
  #pragma unroll
  for (int kk = 0; kk < 8; kk++) {
    bf16x8 nb0 = {}, nb1 = {}, nah = {}, nal = {};
    if (kk < 7) {
      const int ko = (kk + 1) * 32;
      nb0 = *reinterpret_cast<const bf16x8*>(s0p + ko);
      nb1 = *reinterpret_cast<const bf16x8*>(s1p + ko);
      nah = *reinterpret_cast<const bf16x8*>(ahp + ko);
      nal = *reinterpret_cast<const bf16x8*>(alp + ko);
    }
    #pragma unroll
    for (int ns = 0; ns < 4; ns++) {
      const bf16x8 bh = *reinterpret_cast<const bf16x8*>(&Bs[cur][(size_t)((ns * 2 + 0) * 64 + lane) * 8]);
      const bf16x8 bl = *reinterpret_cast<const bf16x8*>(&Bs[cur][(size_t)((ns * 2 + 1) * 64 + lane) * 8]);
      acc[ns] = __builtin_amdgcn_mfma_f32_16x16x32_bf16(ah, bh, acc[ns], 0, 0, 0);
      acc[ns] = __builtin_amdgcn_mfma_f32_16x16x32_bf16(ah, bl, acc[ns], 0, 0, 0);
      acc[ns] = __builtin_amdgcn_mfma_f32_16x16x32_bf16(al, bh, acc[ns], 0, 0, 0);
    }
    if (kk < 7) {
      *reinterpret_cast<bf16x8*>(&Bs[cur ^ 1][(size_t)tid * 8]) = nb0;
      *reinterpret_cast<bf16x8*>(&Bs[cur ^ 1][((size_t)tid + 256) * 8]) = nb1;
      ah = nah; al = nal;
    }
    __syncthreads();
    cur ^= 1;
  }

  if (by < 4 || by >= 8) {
    // Q rows 0..255 / V rows 512..767 of Qkv, [o][n] layout
    const int orow0 = (by < 4 ? by * 64 : (by - 8) * 64 + 512) + w * 16 + 4 * g;
    #pragma unroll
    for (int ns = 0; ns < 4; ns++)
      #pragma unroll
      for (int r = 0; r < 4; r++)
        Qkv[(size_t)(orow0 + r) * N_TOK + n0 + ns * 16 + lq] = f2bf(acc[ns][r]);
  } else {
    // K written transposed: Kt[h][n][d], 4 contiguous d per ushort4 store
    const int ok0 = (by - 4) * 64 + w * 16 + 4 * g;
    const int hh = ok0 >> 5, d0 = ok0 & 31;
    #pragma unroll
    for (int ns = 0; ns < 4; ns++) {
      ushort4 u;
      u.x = f2bf(acc[ns][0]); u.y = f2bf(acc[ns][1]);
      u.z = f2bf(acc[ns][2]); u.w = f2bf(acc[ns][3]);
      *reinterpret_cast<ushort4*>(&Kt[((size_t)hh * N_TOK + n0 + ns * 16 + lq) * HDIM + d0]) = u;
    }
  }
}

// ---------------------------------------------------------------------------
// Kernel 2: depthwise 3x3 conv, pad=1, initializes d_out
// ---------------------------------------------------------------------------
__global__ __launch_bounds__(256) void dwconv_kernel(
    const float* __restrict__ x, const float* __restrict__ wl,
    float* __restrict__ out)
{
  const int idx = blockIdx.x * 256 + threadIdx.x;
  const int c  = idx >> 12;
  const int yy = (idx >> 6) & 63;
  const int xx = idx & 63;
  const float* xc = x + c * 4096;
  const float* wc = wl + c * 9;
  float acc = 0.f;
  #pragma unroll
  for (int dy = 0; dy < 3; dy++) {
    const int y = yy + dy - 1;
    if (y < 0 || y > 63) continue;
    #pragma unroll
    for (int dx = 0; dx < 3; dx++) {
      const int x2 = xx + dx - 1;
      if (x2 < 0 || x2 > 63) continue;
      acc += wc[dy * 3 + dx] * xc[y * 64 + x2];
    }
  }
  out[idx] = acc;
}

// ---------------------------------------------------------------------------
// Kernel 3: MFMA flash attention (LDS-staged, pipelined, no-max softmax,
// permuted-K so P lands in PV B-frag layout).  Raw v_exp + v_cvt_pk.
// ---------------------------------------------------------------------------
__global__ __launch_bounds__(256) void attn_mfma(
    const unsigned short* __restrict__ Qkv,
    const unsigned short* __restrict__ Kt,
    float* __restrict__ Opart,
    float* __restrict__ lpart)
{
  const int h  = blockIdx.z;
  const int ks = blockIdx.y;
  const int tid  = threadIdx.x;
  const int w    = tid >> 6;
  const int lane = tid & 63;
  const int lq   = lane & 15;
  const int g    = lane >> 4;
  const int nq   = blockIdx.x * 64 + w * 16 + lq;

  __shared__ unsigned short KbL[2][2048];
  __shared__ unsigned short VbL[2][2048];

  bf16x8 qf;
  {
    const unsigned short* Qh = Qkv + h * HDIM * N_TOK;
    #pragma unroll
    for (int j = 0; j < 8; j++) qf[j] = (short)Qh[(8 * g + j) * N_TOK + nq];
  }

  const unsigned short* KtH = Kt + (size_t)h * N_TOK * HDIM;
  const unsigned short* VH  = Qkv + (512 + h * HDIM) * N_TOK;
  const int kbase = ks * (N_TOK / KSPLIT);       // 2048 keys per split
  const int pr = 8 * (lq >> 2) + (lq & 3);

  const int skey  = (w & 1) * 4 + (w >> 1) * 32 + pr;
  const unsigned short* ksrc = &KtH[(size_t)(kbase + skey) * HDIM + 8 * g];
  const int sdrow = (w & 1) * 16 + lq;
  const unsigned short* vsrc = &VH[(size_t)sdrow * N_TOK + kbase + (w >> 1) * 32 + 8 * g];

  {
    const bf16x8 kr = *reinterpret_cast<const bf16x8*>(ksrc);
    const bf16x8 vr = *reinterpret_cast<const bf16x8*>(vsrc);
    *reinterpret_cast<bf16x8*>(&KbL[0][tid * 8]) = kr;
    *reinterpret_cast<bf16x8*>(&VbL[0][tid * 8]) = vr;
  }
  __syncthreads();

  f32x4 o0 = {0.f,0.f,0.f,0.f}, o1 = {0.f,0.f,0.f,0.f};
  f32x4 la0 = {0.f,0.f,0.f,0.f}, la1 = {0.f,0.f,0.f,0.f};
  const f32x4 zz = {0.f,0.f,0.f,0.f};
  constexpr int NT = (N_TOK / KSPLIT) / 64;      // 32 tiles

  int cur = 0;
  #pragma unroll 2
  for (int t = 0; t < NT; ++t) {
    bf16x8 kr = {}, vr = {};
    if (t + 1 < NT) {
      kr = *reinterpret_cast<const bf16x8*>(ksrc + (size_t)(t + 1) * 64 * HDIM);
      vr = *reinterpret_cast<const bf16x8*>(vsrc + (t + 1) * 64);
    }

    const unsigned short* kb = &KbL[cur][0];
    const unsigned short* vb = &VbL[cur][0];
    const bf16x8 kf0 = *reinterpret_cast<const bf16x8*>(&kb[lane * 8]);
    const bf16x8 kf1 = *reinterpret_cast<const bf16x8*>(&kb[lane * 8 + 512]);
    const bf16x8 kf2 = *reinterpret_cast<const bf16x8*>(&kb[lane * 8 + 1024]);
    const bf16x8 kf3 = *reinterpret_cast<const bf16x8*>(&kb[lane * 8 + 1536]);

    const f32x4 s0 = __builtin_amdgcn_mfma_f32_16x16x32_bf16(kf0, qf, zz, 0, 0, 0);
    const f32x4 s1 = __builtin_amdgcn_mfma_f32_16x16x32_bf16(kf1, qf, zz, 0, 0, 0);
    const f32x4 s2 = __builtin_amdgcn_mfma_f32_16x16x32_bf16(kf2, qf, zz, 0, 0, 0);
    const f32x4 s3 = __builtin_amdgcn_mfma_f32_16x16x32_bf16(kf3, qf, zz, 0, 0, 0);

    f32x4 p0, p1, p2, p3;
    #pragma unroll
    for (int r = 0; r < 4; r++) {
      p0[r] = fexp2(s0[r]); p1[r] = fexp2(s1[r]);
      p2[r] = fexp2(s2[r]); p3[r] = fexp2(s3[r]);
    }
    la0 += p0; la0 += p1; la1 += p2; la1 += p3;

    const u32x4 pua = { cvt_pk(p0[0], p0[1]), cvt_pk(p0[2], p0[3]),
                        cvt_pk(p1[0], p1[1]), cvt_pk(p1[2], p1[3]) };
    const u32x4 pub = { cvt_pk(p2[0], p2[1]), cvt_pk(p2[2], p2[3]),
                        cvt_pk(p3[0], p3[1]), cvt_pk(p3[2], p3[3]) };
    const bf16x8 pfa = __builtin_bit_cast(bf16x8, pua);
    const bf16x8 pfb = __builtin_bit_cast(bf16x8, pub);

    const bf16x8 vf0a = *reinterpret_cast<const bf16x8*>(&vb[lane * 8]);
    const bf16x8 vf1a = *reinterpret_cast<const bf16x8*>(&vb[lane * 8 + 512]);
    const bf16x8 vf0b = *reinterpret_cast<const bf16x8*>(&vb[lane * 8 + 1024]);
    const bf16x8 vf1b = *reinterpret_cast<const bf16x8*>(&vb[lane * 8 + 1536]);

    o0 = __builtin_amdgcn_mfma_f32_16x16x32_bf16(vf0a, pfa, o0, 0, 0, 0);
    o0 = __builtin_amdgcn_mfma_f32_16x16x32_bf16(vf0b, pfb, o0, 0, 0, 0);
    o1 = __builtin_amdgcn_mfma_f32_16x16x32_bf16(vf1a, pfa, o1, 0, 0, 0);
    o1 = __builtin_amdgcn_mfma_f32_16x16x32_bf16(vf1b, pfb, o1, 0, 0, 0);

    if (t + 1 < NT) {
      *reinterpret_cast<bf16x8*>(&KbL[cur ^ 1][tid * 8]) = kr;
      *reinterpret_cast<bf16x8*>(&VbL[cur ^ 1][tid * 8]) = vr;
    }
    __syncthreads();
    cur ^= 1;
  }

  float ls = (la0[0] + la0[1]) + (la0[2] + la0[3]) + (la1[0] + la1[1]) + (la1[2] + la1[3]);
  ls += __shfl_xor(ls, 16);
  ls += __shfl_xor(ls, 32);

  const int ob = (ks * HEADS + h) * HDIM;
  #pragma unroll
  for (int r = 0; r < 4; r++) {
    Opart[(size_t)(ob + 4 * g + r) * N_TOK + nq]      = o0[r];
    Opart[(size_t)(ob + 16 + 4 * g + r) * N_TOK + nq] = o1[r];
  }
  if (g == 0) lpart[(ks * HEADS + h) * N_TOK + nq] = ls;
}

// ---------------------------------------------------------------------------
// Kernel 4: fused combine (sum partials, /L) + transpose + hi/lo split
// Opart [ks][256][4096] -> Ohi/Olo [4096][256]
// ---------------------------------------------------------------------------
__global__ __launch_bounds__(256) void combsplit(
    const float* __restrict__ Opart, const float* __restrict__ lpart,
    unsigned short* __restrict__ dhi, unsigned short* __restrict__ dlo)
{
  __shared__ float T[64][69];
  __shared__ float Linv[2][64];
  const int o0 = blockIdx.y * 64, n0 = blockIdx.x * 64;
  const int t = threadIdx.x;
  if (t < 128) {
    const int hl = t >> 6, nl = t & 63;
    const int hh = (o0 >> 5) + hl;
    float L = 0.f;
    #pragma unroll
    for (int ks = 0; ks < KSPLIT; ks++)
      L += lpart[(ks * HEADS + hh) * N_TOK + n0 + nl];
    Linv[hl][nl] = 1.f / L;
  }
  __syncthreads();
  {
    const int cl = t >> 2, ng = (t & 3) * 16;
    const int hrow = cl >> 5;
    #pragma unroll
    for (int jj = 0; jj < 4; jj++) {
      float4 a = make_float4(0.f, 0.f, 0.f, 0.f);
      #pragma unroll
      for (int ks = 0; ks < KSPLIT; ks++) {
        const float4 v = *reinterpret_cast<const float4*>(
            &Opart[(size_t)ks * C_DIM * N_TOK + (size_t)(o0 + cl) * N_TOK + n0 + ng + jj * 4]);
        a.x += v.x; a.y += v.y; a.z += v.z; a.w += v.w;
      }
      T[cl][ng + jj * 4 + 0] = a.x * Linv[hrow][ng + jj * 4 + 0];
      T[cl][ng + jj * 4 + 1] = a.y * Linv[hrow][ng + jj * 4 + 1];
      T[cl][ng + jj * 4 + 2] = a.z * Linv[hrow][ng + jj * 4 + 2];
      T[cl][ng + jj * 4 + 3] = a.w * Linv[hrow][ng + jj * 4 + 3];
    }
  }
  __syncthreads();
  {
    const int nl = t >> 2, cg = (t & 3) * 16;
    u16x8 h0, h1, l0, l1;
    #pragma unroll
    for (int j = 0; j < 8; j++) {
      const float v = T[cg + j][nl];
      h0[j] = f2bf(v); l0[j] = f2bf(v - bf2f(h0[j]));
    }
    #pragma unroll
    for (int j = 0; j < 8; j++) {
      const float v = T[cg + 8 + j][nl];
      h1[j] = f2bf(v); l1[j] = f2bf(v - bf2f(h1[j]));
    }
    const size_t base = (size_t)(n0 + nl) * C_DIM + o0 + cg;
    *reinterpret_cast<u16x8*>(&dhi[base])     = h0;
    *reinterpret_cast<u16x8*>(&dhi[base + 8]) = h1;
    *reinterpret_cast<u16x8*>(&dlo[base])     = l0;
    *reinterpret_cast<u16x8*>(&dlo[base + 8]) = l1;
  }
}

// ---------------------------------------------------------------------------
// Kernel 5: out projection, LDS-staged + pipelined + K-split 2,
// atomic-accumulates onto conv-initialized d_out.
// ---------------------------------------------------------------------------
__global__ __launch_bounds__(256) void out_mfma(
    const unsigned short* __restrict__ Whi, const unsigned short* __restrict__ Wlo,
    const unsigned short* __restrict__ Ohi, const unsigned short* __restrict__ Olo,
    float* __restrict__ out)
{
  const int n0 = blockIdx.x * 64;
  const int by = blockIdx.y;
  const int kb = blockIdx.z * 128;
  const int tid = threadIdx.x;
  const int w = tid >> 6, lane = tid & 63, lq = lane & 15, g = lane >> 4;
  const int c0 = by * 64 + w * 16;

  __shared__ unsigned short Bs[2][4096];

  const int e0l = tid & 63, e0f = tid >> 6;
  const unsigned short* s0p; const unsigned short* s1p;
  {
    const int lq_ = e0l & 15, g_ = e0l >> 4;
    const int f0 = e0f, f1 = e0f + 4;
    s0p = ((f0 & 1) ? Olo : Ohi) + (size_t)(n0 + (f0 >> 1) * 16 + lq_) * C_DIM + kb + 8 * g_;
    s1p = ((f1 & 1) ? Olo : Ohi) + (size_t)(n0 + (f1 >> 1) * 16 + lq_) * C_DIM + kb + 8 * g_;
  }
  const unsigned short* ahp = &Whi[(size_t)(768 + c0 + lq) * C_DIM + kb + 8 * g];
  const unsigned short* alp = &Wlo[(size_t)(768 + c0 + lq) * C_DIM + kb + 8 * g];

  f32x4 acc[4] = {{0.f,0.f,0.f,0.f},{0.f,0.f,0.f,0.f},{0.f,0.f,0.f,0.f},{0.f,0.f,0.f,0.f}};

  bf16x8 ah = *reinterpret_cast<const bf16x8*>(ahp);
  bf16x8 al = *reinterpret_cast<const bf16x8*>(alp);
  {
    const bf16x8 b0 = *reinterpret_cast<const bf16x8*>(s0p);
    const bf16x8 b1 = *reinterpret_cast<const bf16x8*>(s1p);
    *reinterpret_cast<bf16x8*>(&Bs[0][(size_t)tid * 8]) = b0;
    *reinterpret_cast<bf16x8*>(&Bs[0][((size_t)tid + 256) * 8]) = b1;
  }
  __syncthreads();

  int cur = 0;
  #pragma unroll
  for (int kk = 0; kk < 4; kk++) {
    bf16x8 nb0 = {}, nb1 = {}, nah = {}, nal = {};
    if (kk < 3) {
      const int ko = (kk + 1) * 32;
      nb0 = *reinterpret_cast<const bf16x8*>(s0p + ko);
      nb1 = *reinterpret_cast<const bf16x8*>(s1p + ko);
      nah = *reinterpret_cast<const bf16x8*>(ahp + ko);
      nal = *reinterpret_cast<const bf16x8*>(alp + ko);
    }
    #pragma unroll
    for (int ns = 0; ns < 4; ns++) {
      const bf16x8 bh = *reinterpret_cast<const bf16x8*>(&Bs[cur][(size_t)((ns * 2 + 0) * 64 + lane) * 8]);
      const bf16x8 bl = *reinterpret_cast<const bf16x8*>(&Bs[cur][(size_t)((ns * 2 + 1) * 64 + lane) * 8]);
      acc[ns] = __builtin_amdgcn_mfma_f32_16x16x32_bf16(ah, bh, acc[ns], 0, 0, 0);
      acc[ns] = __builtin_amdgcn_mfma_f32_16x16x32_bf16(ah, bl, acc[ns], 0, 0, 0);
      acc[ns] = __builtin_amdgcn_mfma_f32_16x16x32_bf16(al, bh, acc[ns], 0, 0, 0);
    }
    if (kk < 3) {
      *reinterpret_cast<bf16x8*>(&Bs[cur ^ 1][(size_t)tid * 8]) = nb0;
      *reinterpret_cast<bf16x8*>(&Bs[cur ^ 1][((size_t)tid + 256) * 8]) = nb1;
      ah = nah; al = nal;
    }
    __syncthreads();
    cur ^= 1;
  }

  #pragma unroll
  for (int ns = 0; ns < 4; ns++)
    #pragma unroll
    for (int r = 0; r < 4; r++)
      unsafeAtomicAdd(&out[(size_t)(c0 + 4 * g + r) * N_TOK + n0 + ns * 16 + lq], acc[ns][r]);
}

// ---------------------------------------------------------------------------
extern "C" void kernel_launch(void* const* d_in, const int* in_sizes, int n_in,
                              void* d_out, int out_size, void* d_ws, size_t ws_size,
                              hipStream_t stream) {
  const float* x  = (const float*)d_in[0];
  const float* wq = (const float*)d_in[1];
  const float* wk = (const float*)d_in[2];
  const float* wv = (const float*)d_in[3];
  const float* wo = (const float*)d_in[4];
  const float* wl = (const float*)d_in[5];
  float* out = (float*)d_out;

  float* Opart = (float*)d_ws;                                  // 2*256*4096 f
  float* lpart = Opart + (size_t)KSPLIT * C_DIM * N_TOK;        // 2*8*4096 f
  unsigned short* Qkv = (unsigned short*)(lpart + KSPLIT * HEADS * N_TOK);  // 768*4096
  unsigned short* Kt  = Qkv + 768 * N_TOK;                      // 8*4096*32
  unsigned short* Whi = Kt + (size_t)HEADS * N_TOK * HDIM;      // 1024*256
  unsigned short* Wlo = Whi + 1024 * C_DIM;
  unsigned short* Xhi = Wlo + 1024 * C_DIM;                     // 4096*256
  unsigned short* Xlo = Xhi + (size_t)N_TOK * C_DIM;
  unsigned short* Ohi = Xlo + (size_t)N_TOK * C_DIM;
  unsigned short* Olo = Ohi + (size_t)N_TOK * C_DIM;            // total ~26.5 MB

  wsplit<<<256, 256, 0, stream>>>(wq, wk, wv, wo, Whi, Wlo);
  tsplit<<<dim3(64, 4), 256, 0, stream>>>(x, Xhi, Xlo);
  qkv_mfma<<<dim3(64, 12), 256, 0, stream>>>(Whi, Wlo, Xhi, Xlo, Qkv, Kt);
  dwconv_kernel<<<4096, 256, 0, stream>>>(x, wl, out);
  attn_mfma<<<dim3(64, KSPLIT, HEADS), 256, 0, stream>>>(Qkv, Kt, Opart, lpart);
  combsplit<<<dim3(64, 4), 256, 0, stream>>>(Opart, lpart, Ohi, Olo);
  out_mfma<<<dim3(64, 4, 2), 256, 0, stream>>>(Whi, Wlo, Ohi, Olo, out);
}